// Round 1
// baseline (508.513 us; speedup 1.0000x reference)
//
#include <hip/hip_runtime.h>
#include <hip/hip_bf16.h>

#define CIN   512
#define COUT  512
#define LEN   8192
#define NB    16
#define KW    3

#define BM    128          // co rows per block
#define BN    128          // l cols per block
#define BKC   64           // ci per LDS chunk
#define XCOLS 132          // BN + 2 halo (+2 align)
#define XROWB (BKC * 2)    // 128 bytes of bf16 per col

typedef __attribute__((ext_vector_type(4))) float f32x4;
typedef __attribute__((ext_vector_type(8))) short bf16x8;

// ---- weight dequant-reorder: qweight[co][ci][t] (int32) -> wb[t][co][ci] (bf16, unscaled) ----
__global__ __launch_bounds__(256) void wconv_kernel(const int* __restrict__ q,
                                                    unsigned short* __restrict__ wb) {
    int idx = blockIdx.x * 256 + threadIdx.x;
    if (idx >= COUT * CIN * KW) return;
    int t  = idx >> 18;        // / (COUT*CIN)
    int r  = idx & 262143;
    int co = r >> 9;
    int ci = r & 511;
    float f = (float)q[(co * CIN + ci) * KW + t];
    union { float f; unsigned u; } cv; cv.f = f;
    // RNE float->bf16 (int8 values are exact anyway)
    wb[idx] = (unsigned short)((cv.u + 0x7fffu + ((cv.u >> 16) & 1u)) >> 16);
}

// ---- main conv kernel: implicit GEMM, 128x128 tile, 4 waves, mfma 16x16x32 bf16 ----
__global__ __launch_bounds__(256, 2) void conv_kernel(
    const float* __restrict__ x,
    const unsigned short* __restrict__ wb,
    const float* __restrict__ scale_p,
    const float* __restrict__ bias,
    float* __restrict__ out)
{
    // X tile, transposed: [col][ci] bf16, XOR-swizzled in the 16B slot bits
    __shared__ char xT[XCOLS * XROWB];   // 16896 B

    const int bid = blockIdx.x;
    // XCD swizzle: consecutive logical blocks (co-tiles sharing an x panel) on same XCD.
    // grid = 4096 = 8 * 512 (exact), so the simple bijective form is valid.
    const int logical = (bid & 7) * 512 + (bid >> 3);
    const int co_tile = logical & 3;
    const int n_tile  = logical >> 2;           // 0..1023
    const int b   = n_tile >> 6;                // 64 l-tiles per batch
    const int l0  = (n_tile & 63) * BN;
    const int co0 = co_tile * BM;

    const int tid  = threadIdx.x;
    const int lane = tid & 63;
    const int wid  = tid >> 6;
    const int wr = wid >> 1, wc = wid & 1;      // wave -> 64x64 sub-tile
    const int lhi = lane >> 4;                  // 0..3
    const int llo = lane & 15;

    f32x4 acc[4][4] = {};                       // [m][n], each wave 64x64

    const float* xb = x + (size_t)b * CIN * LEN;

    for (int ci0 = 0; ci0 < CIN; ci0 += BKC) {
        __syncthreads();
        // ---- stage X chunk, transposed + bf16 + swizzle ----
        for (int it = tid; it < XCOLS * (BKC / 8); it += 256) {
            int c = it % XCOLS;                 // 0..131 ; global l = l0-1+c
            int o = it / XCOLS;                 // ci octet 0..7
            int l = l0 - 1 + c;
            float v[8];
            if (l >= 0 && l < LEN) {
                const float* src = xb + (size_t)(ci0 + o * 8) * LEN + l;
                #pragma unroll
                for (int j = 0; j < 8; ++j) v[j] = src[(size_t)j * LEN];
            } else {
                #pragma unroll
                for (int j = 0; j < 8; ++j) v[j] = 0.f;   // conv zero-padding
            }
            union { bf16x8 v8; unsigned short s[8]; } pk;
            #pragma unroll
            for (int j = 0; j < 8; ++j) {
                union { float f; unsigned u; } cv; cv.f = v[j];
                pk.s[j] = (unsigned short)((cv.u + 0x7fffu + ((cv.u >> 16) & 1u)) >> 16);
            }
            int byte = c * XROWB + ((o * 16) ^ ((c & 7) << 4));
            *reinterpret_cast<bf16x8*>(xT + byte) = pk.v8;
        }
        __syncthreads();

        // ---- compute: 3 taps x 2 ci-substeps, 16 MFMA each per wave ----
        #pragma unroll
        for (int t = 0; t < KW; ++t) {
            #pragma unroll
            for (int s = 0; s < BKC / 32; ++s) {
                bf16x8 af[4];
                #pragma unroll
                for (int m = 0; m < 4; ++m) {
                    int co = co0 + wr * 64 + m * 16 + llo;
                    int ci = ci0 + s * 32 + 8 * lhi;
                    af[m] = *reinterpret_cast<const bf16x8*>(
                        wb + ((size_t)t * COUT + co) * CIN + ci);
                }
                bf16x8 bfr[4];
                #pragma unroll
                for (int n = 0; n < 4; ++n) {
                    int col = wc * 64 + n * 16 + llo + t;   // tap shift via halo col
                    int k2  = (s * 32 + 8 * lhi) * 2;
                    int byte = col * XROWB + (k2 ^ ((col & 7) << 4));
                    bfr[n] = *reinterpret_cast<const bf16x8*>(xT + byte);
                }
                #pragma unroll
                for (int m = 0; m < 4; ++m)
                    #pragma unroll
                    for (int n = 0; n < 4; ++n)
                        acc[m][n] = __builtin_amdgcn_mfma_f32_16x16x32_bf16(
                            af[m], bfr[n], acc[m][n], 0, 0, 0);
            }
        }
    }

    // ---- epilogue: scale + bias, fp32 stores ----
    const float sc = scale_p[0];
    #pragma unroll
    for (int m = 0; m < 4; ++m) {
        #pragma unroll
        for (int j = 0; j < 4; ++j) {
            int co = co0 + wr * 64 + m * 16 + lhi * 4 + j;   // D row = (lane>>4)*4 + reg
            float bv = bias[co];
            size_t orow = ((size_t)b * COUT + co) * LEN + l0 + wc * 64;
            #pragma unroll
            for (int n = 0; n < 4; ++n) {
                int l = n * 16 + llo;                        // D col = lane&15
                out[orow + l] = sc * acc[m][n][j] + bv;
            }
        }
    }
}

extern "C" void kernel_launch(void* const* d_in, const int* in_sizes, int n_in,
                              void* d_out, int out_size, void* d_ws, size_t ws_size,
                              hipStream_t stream) {
    const float* x    = (const float*)d_in[0];
    const int*   qw   = (const int*)d_in[1];
    const float* sc   = (const float*)d_in[2];
    const float* bias = (const float*)d_in[3];
    float* out = (float*)d_out;
    unsigned short* wb = (unsigned short*)d_ws;   // 512*512*3*2 = 1.5 MB

    const int wtot = COUT * CIN * KW;
    wconv_kernel<<<(wtot + 255) / 256, 256, 0, stream>>>(qw, wb);

    const int grid = (COUT / BM) * (NB * LEN / BN);   // 4 * 1024 = 4096
    conv_kernel<<<grid, 256, 0, stream>>>(x, wb, sc, bias, out);
}